// Round 13
// baseline (56.632 us; speedup 1.0000x reference)
//
#include <hip/hip_runtime.h>
#include <hip/hip_fp16.h>

#define HH 512
#define WW 512
#define NPIX (HH*WW)
#define NBANDS 64
#define BAND (HH/NBANDS)     // 8 output rows per wave
#define NS 20                // ceil((BAND+10)/4)*4 streamed steps
#define PINF2 0x7C007C00u    // packed f16 +inf
#define NINF2 0xFC00FC00u    // packed f16 -inf

// ---- packed f16 ops as VOP3P inline asm (proven rounds 8-12) ----
typedef unsigned uh2;
__device__ __forceinline__ uh2 pmin(uh2 a, uh2 b){ uh2 r; asm("v_pk_min_f16 %0, %1, %2" : "=v"(r) : "v"(a), "v"(b)); return r; }
__device__ __forceinline__ uh2 pmax(uh2 a, uh2 b){ uh2 r; asm("v_pk_max_f16 %0, %1, %2" : "=v"(r) : "v"(a), "v"(b)); return r; }
__device__ __forceinline__ uh2 padd(uh2 a, uh2 b){ uh2 r; asm("v_pk_add_f16 %0, %1, %2" : "=v"(r) : "v"(a), "v"(b)); return r; }
__device__ __forceinline__ uh2 psub(uh2 a, uh2 b){ uh2 r; asm("v_pk_add_f16 %0, %1, %2 neg_lo:[0,1] neg_hi:[0,1]" : "=v"(r) : "v"(a), "v"(b)); return r; }
__device__ __forceinline__ uh2 pnfma(uh2 s, uh2 d){ uh2 r; asm("v_pk_fma_f16 %0, %1, %2, %2 neg_lo:[1,0,0] neg_hi:[1,0,0]" : "=v"(r) : "v"(s), "v"(d)); return r; }
__device__ __forceinline__ uh2 pmin3(uh2 a, uh2 b, uh2 c){ return pmin(pmin(a,b),c); }
__device__ __forceinline__ uh2 pmax3(uh2 a, uh2 b, uh2 c){ return pmax(pmax(a,b),c); }
__device__ __forceinline__ uh2 alignh(uh2 lo, uh2 hi){ return (lo >> 16) | (hi << 16); }   // (lo.y, hi.x)
__device__ __forceinline__ uh2 pk2(float x, float y){
    __half2 h = __halves2half2(__float2half_rn(x), __float2half_rn(y));
    union { __half2 h; uh2 u; } c; c.h = h; return c.u;
}
__device__ __forceinline__ float lo_f(uh2 v){ union { uh2 u; __half2 h; } c; c.u = v; return __low2float(c.h); }
__device__ __forceinline__ float hi_f(uh2 v){ union { uh2 u; __half2 h; } c; c.u = v; return __high2float(c.h); }

// ---- DPP full-wave lane shifts (VALU, no DS pipe); invalid lane <- old ----
__device__ __forceinline__ uh2 dshr1(uh2 v, unsigned old){   // lane i <- lane i-1 (wave_shr:1)
    return (uh2)__builtin_amdgcn_update_dpp((int)old, (int)v, 0x138, 0xF, 0xF, false);
}
__device__ __forceinline__ uh2 dshl1(uh2 v, unsigned old){   // lane i <- lane i+1 (wave_shl:1)
    return (uh2)__builtin_amdgcn_update_dpp((int)old, (int)v, 0x130, 0xF, 0xF, false);
}

// one full 512-wide row: lane l holds halves [8l..8l+7] in 4 packed regs
struct R4 { uh2 a, b, c, d; };
__device__ __forceinline__ R4 r4splat(uh2 v){ R4 r; r.a=v; r.b=v; r.c=v; r.d=v; return r; }
__device__ __forceinline__ R4 ldrow(const float* p){
    float4 u = *(const float4*)p;
    float4 v = *(const float4*)(p + 4);
    R4 r; r.a = pk2(u.x,u.y); r.b = pk2(u.z,u.w); r.c = pk2(v.x,v.y); r.d = pk2(v.z,v.w);
    return r;
}
__device__ __forceinline__ R4 vmin3(const R4& x, const R4& y, const R4& z){
    R4 r; r.a=pmin3(x.a,y.a,z.a); r.b=pmin3(x.b,y.b,z.b); r.c=pmin3(x.c,y.c,z.c); r.d=pmin3(x.d,y.d,z.d); return r;
}
__device__ __forceinline__ R4 vmax3(const R4& x, const R4& y, const R4& z){
    R4 r; r.a=pmax3(x.a,y.a,z.a); r.b=pmax3(x.b,y.b,z.b); r.c=pmax3(x.c,y.c,z.c); r.d=pmax3(x.d,y.d,z.d); return r;
}
__device__ __forceinline__ R4 rmin(const R4& x, const R4& y){
    R4 r; r.a=pmin(x.a,y.a); r.b=pmin(x.b,y.b); r.c=pmin(x.c,y.c); r.d=pmin(x.d,y.d); return r;
}
__device__ __forceinline__ R4 rmax3(const R4& x, const R4& y, const R4& z){ return vmax3(x,y,z); }
__device__ __forceinline__ R4 relusub(const R4& p, const R4& d){
    R4 r; r.a=pmax(psub(p.a,d.a),0u); r.b=pmax(psub(p.b,d.b),0u);
          r.c=pmax(psub(p.c,d.c),0u); r.d=pmax(psub(p.d,d.d),0u); return r;
}
// s += d*(1-s)  (relu provably redundant for s,d in [0,1])
__device__ __forceinline__ void skupd2(R4& s, const R4& d){
    s.a = padd(s.a, pnfma(s.a,d.a));
    s.b = padd(s.b, pnfma(s.b,d.b));
    s.c = padd(s.c, pnfma(s.c,d.c));
    s.d = padd(s.d, pnfma(s.d,d.d));
}
// erode horizontal: min(left,right) excluding center (center is in the vertical min)
__device__ __forceinline__ R4 hminLR(const R4& x){
    uh2 L  = dshr1(x.d, PINF2);
    uh2 Rv = dshl1(x.a, PINF2);
    uh2 s0=alignh(L,x.a), s1=alignh(x.a,x.b), s2=alignh(x.b,x.c), s3=alignh(x.c,x.d), s4=alignh(x.d,Rv);
    R4 m; m.a=pmin(s0,s1); m.b=pmin(s1,s2); m.c=pmin(s2,s3); m.d=pmin(s3,s4); return m;
}
// dilate horizontal: 3-window max including center
__device__ __forceinline__ R4 hmax3w(const R4& x){
    uh2 L  = dshr1(x.d, NINF2);
    uh2 Rv = dshl1(x.a, NINF2);
    uh2 s0=alignh(L,x.a), s1=alignh(x.a,x.b), s2=alignh(x.b,x.c), s3=alignh(x.c,x.d), s4=alignh(x.d,Rv);
    R4 m; m.a=pmax3(s0,x.a,s1); m.b=pmax3(s1,x.b,s2); m.c=pmax3(s2,x.c,s3); m.d=pmax3(s3,x.d,s4); return m;
}

// ---------- FAST step: interior bands, no row guards, vertical-first dilate ----------
__device__ __forceinline__ void step_fast(
    int g, int s, int y0, int y1,
    const float* __restrict__ img, const float* __restrict__ oth,
    R4& i2, R4& i1, R4& i0next,
    R4& e1p, R4& e1pp, R4& e2p, R4& e2pp, R4& e3p, R4& e3pp, R4& e4p, R4& e4pp,
    R4& skB, R4& skD1, R4& skD2, R4& skF,
    float& sa, float& sb)
{
    R4 i0 = i0next;
    if (s + 1 < BAND + 10) i0next = ldrow(img + (size_t)(g + 1) * WW);
    const int  yf  = g - 5;
    const bool fin = (yf >= y0) && (yf < y1);
    float4 o1, o2;
    if (fin) {
        o1 = *(const float4*)(oth + (size_t)yf * WW);
        o2 = *(const float4*)(oth + (size_t)yf * WW + 4);
    }

    R4 e1n = rmin(vmin3(i2, i1, i0), hminLR(i1));
    R4 d1  = hmax3w(vmax3(e1pp, e1p, e1n));        // dilate(e1) @ g-2
    skB = relusub(i2, d1);

    R4 e2n = rmin(vmin3(e1pp, e1p, e1n), hminLR(e1p));
    R4 d2  = hmax3w(vmax3(e2pp, e2p, e2n));        // @ g-3
    skupd2(skD1, relusub(e1pp, d2));

    R4 e3n = rmin(vmin3(e2pp, e2p, e2n), hminLR(e2p));
    R4 d3  = hmax3w(vmax3(e3pp, e3p, e3n));        // @ g-4
    skupd2(skD2, relusub(e2pp, d3));

    R4 e4n = rmin(vmin3(e3pp, e3p, e3n), hminLR(e3p));
    R4 d4  = hmax3w(vmax3(e4pp, e4p, e4n));        // @ g-5
    skupd2(skF, relusub(e3pp, d4));

    if (fin) {
        float f0=lo_f(skF.a), f1=hi_f(skF.a), f2=lo_f(skF.b), f3=hi_f(skF.b);
        float f4=lo_f(skF.c), f5=hi_f(skF.c), f6=lo_f(skF.d), f7=hi_f(skF.d);
        sa += ((f0+f1)+(f2+f3)) + ((f4+f5)+(f6+f7));
        sb += ((f0*o1.x + f1*o1.y) + (f2*o1.z + f3*o1.w))
            + ((f4*o2.x + f5*o2.y) + (f6*o2.z + f7*o2.w));
    }
    i2 = i1; i1 = i0;
    e1pp = e1n; e2pp = e2n; e3pp = e3n; e4pp = e4n;   // caller swaps (p,pp)
}

// ---------- GUARD step: bands 0 / NBANDS-1 (round-11-proven logic, DPP) ----------
__device__ __forceinline__ void step_guard(
    int g, int s, int y0, int y1,
    const float* __restrict__ img, const float* __restrict__ oth,
    R4& i2, R4& i1, R4& i0next,
    R4& e1p, R4& e1pp, R4& e2p, R4& e2pp, R4& e3p, R4& e3pp,
    R4& h1p, R4& h1pp, R4& h2p, R4& h2pp, R4& h3p, R4& h3pp,
    R4& h4p, R4& h4pp,
    R4& skB, R4& skD1, R4& skD2, R4& skF,
    float& sa, float& sb)
{
    R4 i0 = i0next;
    {
        const int gn = g + 1;
        const bool ld = (s + 1 < BAND + 10) && (gn >= 0) && (gn < HH);
        i0next = ld ? ldrow(img + (size_t)gn * WW) : r4splat(PINF2);
    }
    const int  yf  = g - 5;
    const bool fin = (yf >= y0) && (yf < y1);
    float4 o1, o2;
    if (fin) {
        o1 = *(const float4*)(oth + (size_t)yf * WW);
        o2 = *(const float4*)(oth + (size_t)yf * WW + 4);
    }

    R4 e1n = rmin(vmin3(i2, i1, i0), hminLR(i1));
    R4 h1n = hmax3w(e1n);
    if ((unsigned)(g - 1) >= (unsigned)HH) { e1n = r4splat(PINF2); h1n = r4splat(NINF2); }
    R4 d1 = rmax3(h1pp, h1p, h1n);
    skB = relusub(i2, d1);

    R4 e2n = rmin(vmin3(e1pp, e1p, e1n), hminLR(e1p));
    R4 h2n = hmax3w(e2n);
    if ((unsigned)(g - 2) >= (unsigned)HH) { e2n = r4splat(PINF2); h2n = r4splat(NINF2); }
    R4 d2 = rmax3(h2pp, h2p, h2n);
    skupd2(skD1, relusub(e1pp, d2));

    R4 e3n = rmin(vmin3(e2pp, e2p, e2n), hminLR(e2p));
    R4 h3n = hmax3w(e3n);
    if ((unsigned)(g - 3) >= (unsigned)HH) { e3n = r4splat(PINF2); h3n = r4splat(NINF2); }
    R4 d3 = rmax3(h3pp, h3p, h3n);
    skupd2(skD2, relusub(e2pp, d3));

    R4 e4n = rmin(vmin3(e3pp, e3p, e3n), hminLR(e3p));
    R4 h4n = hmax3w(e4n);
    if ((unsigned)(g - 4) >= (unsigned)HH) { h4n = r4splat(NINF2); }
    R4 d4 = rmax3(h4pp, h4p, h4n);
    skupd2(skF, relusub(e3pp, d4));

    if (fin) {
        float f0=lo_f(skF.a), f1=hi_f(skF.a), f2=lo_f(skF.b), f3=hi_f(skF.b);
        float f4=lo_f(skF.c), f5=hi_f(skF.c), f6=lo_f(skF.d), f7=hi_f(skF.d);
        sa += ((f0+f1)+(f2+f3)) + ((f4+f5)+(f6+f7));
        sb += ((f0*o1.x + f1*o1.y) + (f2*o1.z + f3*o1.w))
            + ((f4*o2.x + f5*o2.y) + (f6*o2.z + f7*o2.w));
    }
    i2 = i1; i1 = i0;
    e1pp = e1n; e2pp = e2n; e3pp = e3n;
    h1pp = h1n; h2pp = h2n; h3pp = h3n; h4pp = h4n;
}

__global__ __launch_bounds__(256, 2)
void cldice_stream_k(const float* __restrict__ y_pred,
                     const float* __restrict__ y_true,
                     float2* __restrict__ partials, int B)
{
    const int lane = threadIdx.x & 63;
    const int wid  = threadIdx.x >> 6;
    const int wave = blockIdx.x * 4 + wid;
    const int nPerChain = B * NBANDS;
    if (wave >= 2 * nPerChain) return;
    const int chain = wave / nPerChain;
    const int rem   = wave - chain * nPerChain;
    const int im    = rem >> 6;                 // NBANDS == 64
    const int band  = rem & (NBANDS - 1);
    const int y0 = band * BAND;
    const int y1 = y0 + BAND;

    const float* __restrict__ img = (chain ? y_true : y_pred) + (size_t)im * NPIX + lane * 8;
    const float* __restrict__ oth = (chain ? y_pred : y_true) + (size_t)im * NPIX + lane * 8;

    R4 sk0 = r4splat(0u), sk1 = sk0, sk2 = sk0, sk3 = sk0;
    float sa = 0.f, sb = 0.f;
    const int g0 = y0 - 5;

    if (band == 0 || band == NBANDS - 1) {
        // -------- guarded path (image top/bottom) --------
        R4 i2 = r4splat(PINF2), i1 = i2;
        R4 e1A = i2, e1B = i2, e2A = i2, e2B = i2, e3A = i2, e3B = i2;
        R4 h1A = r4splat(NINF2), h1B = h1A, h2A = h1A, h2B = h1A;
        R4 h3A = h1A, h3B = h1A, h4A = h1A, h4B = h1A;
        R4 i0next = (g0 >= 0) ? ldrow(img + (size_t)g0 * WW) : r4splat(PINF2);

#define STEPG(U, E1P,E1PP, E2P,E2PP, E3P,E3PP, H1P,H1PP, H2P,H2PP, H3P,H3PP, H4P,H4PP, SKB,SKD1,SKD2,SKF) \
        step_guard(g0 + sbase + U, sbase + U, y0, y1, img, oth, i2, i1, i0next, \
                   E1P,E1PP, E2P,E2PP, E3P,E3PP, H1P,H1PP, H2P,H2PP, H3P,H3PP, H4P,H4PP, \
                   SKB,SKD1,SKD2,SKF, sa, sb)
        for (int sbase = 0; sbase < NS; sbase += 4) {
            STEPG(0, e1A,e1B, e2A,e2B, e3A,e3B, h1A,h1B, h2A,h2B, h3A,h3B, h4A,h4B, sk1,sk0,sk3,sk2);
            STEPG(1, e1B,e1A, e2B,e2A, e3B,e3A, h1B,h1A, h2B,h2A, h3B,h3A, h4B,h4A, sk2,sk1,sk0,sk3);
            STEPG(2, e1A,e1B, e2A,e2B, e3A,e3B, h1A,h1B, h2A,h2B, h3A,h3B, h4A,h4B, sk3,sk2,sk1,sk0);
            STEPG(3, e1B,e1A, e2B,e2A, e3B,e3A, h1B,h1A, h2B,h2A, h3B,h3A, h4B,h4A, sk0,sk3,sk2,sk1);
        }
#undef STEPG
    } else {
        // -------- fast path (interior bands; all halo rows are real) --------
        R4 i2 = ldrow(img + (size_t)g0 * WW);       // harmless warm init (rows valid)
        R4 i1 = i2;
        R4 e1A = r4splat(PINF2), e1B = e1A, e2A = e1A, e2B = e1A;
        R4 e3A = e1A, e3B = e1A, e4A = e1A, e4B = e1A;
        R4 i0next = i2;

#define STEPF(U, E1P,E1PP, E2P,E2PP, E3P,E3PP, E4P,E4PP, SKB,SKD1,SKD2,SKF) \
        step_fast(g0 + sbase + U, sbase + U, y0, y1, img, oth, i2, i1, i0next, \
                  E1P,E1PP, E2P,E2PP, E3P,E3PP, E4P,E4PP, SKB,SKD1,SKD2,SKF, sa, sb)
        for (int sbase = 0; sbase < NS; sbase += 4) {
            STEPF(0, e1A,e1B, e2A,e2B, e3A,e3B, e4A,e4B, sk1,sk0,sk3,sk2);
            STEPF(1, e1B,e1A, e2B,e2A, e3B,e3A, e4B,e4A, sk2,sk1,sk0,sk3);
            STEPF(2, e1A,e1B, e2A,e2B, e3A,e3B, e4A,e4B, sk3,sk2,sk1,sk0);
            STEPF(3, e1B,e1A, e2B,e2A, e3B,e3A, e4B,e4A, sk0,sk3,sk2,sk1);
        }
#undef STEPF
    }

#pragma unroll
    for (int off = 32; off; off >>= 1) {
        sa += __shfl_down(sa, off);
        sb += __shfl_down(sb, off);
    }
    if (lane == 0) partials[wave] = make_float2(sb, sa);   // (.x = sum skel*other, .y = sum skel)
}

__global__ void cldice_final_k(const float2* __restrict__ partials, int nW,
                               float* __restrict__ out)
{
    double s0 = 0, s1 = 0, s2 = 0, s3 = 0;
    for (int i = threadIdx.x; i < nW; i += 256) {
        float2 p = partials[i];        s0 += p.x; s1 += p.y;   // chain 0: skel_pred
        float2 q = partials[nW + i];   s2 += q.x; s3 += q.y;   // chain 1: skel_true
    }
#pragma unroll
    for (int off = 32; off; off >>= 1) {
        s0 += __shfl_down(s0, off);
        s1 += __shfl_down(s1, off);
        s2 += __shfl_down(s2, off);
        s3 += __shfl_down(s3, off);
    }
    __shared__ double sm[4][4];
    int wid = threadIdx.x >> 6, lane = threadIdx.x & 63;
    if (lane == 0) { sm[0][wid] = s0; sm[1][wid] = s1; sm[2][wid] = s2; sm[3][wid] = s3; }
    __syncthreads();
    if (threadIdx.x == 0) {
        double S0 = sm[0][0] + sm[0][1] + sm[0][2] + sm[0][3];
        double S1 = sm[1][0] + sm[1][1] + sm[1][2] + sm[1][3];
        double S2 = sm[2][0] + sm[2][1] + sm[2][2] + sm[2][3];
        double S3 = sm[3][0] + sm[3][1] + sm[3][2] + sm[3][3];
        double tprec = (S0 + 1.0) / (S1 + 1.0);
        double tsens = (S2 + 1.0) / (S3 + 1.0);
        out[0] = (float)(1.0 - 2.0 * (tprec * tsens) / (tprec + tsens));
    }
}

extern "C" void kernel_launch(void* const* d_in, const int* in_sizes, int n_in,
                              void* d_out, int out_size, void* d_ws, size_t ws_size,
                              hipStream_t stream)
{
    const float* y_pred = (const float*)d_in[0];
    const float* y_true = (const float*)d_in[1];
    const int B = in_sizes[0] / NPIX;          // 32 images

    float2* partials = (float2*)d_ws;          // 2*B*NBANDS float2 = 32 KB
    const int nWaves = 2 * B * NBANDS;
    const int blocks = (nWaves + 3) / 4;       // 4 waves per 256-thread block
    cldice_stream_k<<<blocks, 256, 0, stream>>>(y_pred, y_true, partials, B);

    cldice_final_k<<<1, 256, 0, stream>>>(partials, B * NBANDS, (float*)d_out);
}

// Round 14
// 45.736 us; speedup vs baseline: 1.2383x; 1.2383x over previous
//
#include <hip/hip_runtime.h>
#include <hip/hip_fp16.h>

#define HH 512
#define WW 512
#define NPIX (HH*WW)
#define NBANDS 32
#define BAND (HH/NBANDS)     // 16 output rows per wave
#define NSTEP (BAND+10)      // 26 productive steps (fin ends at s=25)
#define PINF2 0x7C007C00u    // packed f16 +inf
#define NINF2 0xFC00FC00u    // packed f16 -inf

// ---- packed f16 ops as VOP3P inline asm (proven rounds 8-13) ----
typedef unsigned uh2;
__device__ __forceinline__ uh2 pmin(uh2 a, uh2 b){ uh2 r; asm("v_pk_min_f16 %0, %1, %2" : "=v"(r) : "v"(a), "v"(b)); return r; }
__device__ __forceinline__ uh2 pmax(uh2 a, uh2 b){ uh2 r; asm("v_pk_max_f16 %0, %1, %2" : "=v"(r) : "v"(a), "v"(b)); return r; }
__device__ __forceinline__ uh2 padd(uh2 a, uh2 b){ uh2 r; asm("v_pk_add_f16 %0, %1, %2" : "=v"(r) : "v"(a), "v"(b)); return r; }
__device__ __forceinline__ uh2 psub(uh2 a, uh2 b){ uh2 r; asm("v_pk_add_f16 %0, %1, %2 neg_lo:[0,1] neg_hi:[0,1]" : "=v"(r) : "v"(a), "v"(b)); return r; }
__device__ __forceinline__ uh2 pnfma(uh2 s, uh2 d){ uh2 r; asm("v_pk_fma_f16 %0, %1, %2, %2 neg_lo:[1,0,0] neg_hi:[1,0,0]" : "=v"(r) : "v"(s), "v"(d)); return r; }
__device__ __forceinline__ uh2 pmin3(uh2 a, uh2 b, uh2 c){ return pmin(pmin(a,b),c); }
__device__ __forceinline__ uh2 pmax3(uh2 a, uh2 b, uh2 c){ return pmax(pmax(a,b),c); }
__device__ __forceinline__ uh2 alignh(uh2 lo, uh2 hi){ return (lo >> 16) | (hi << 16); }   // (lo.y, hi.x)
__device__ __forceinline__ uh2 pk2(float x, float y){
    __half2 h = __halves2half2(__float2half_rn(x), __float2half_rn(y));
    union { __half2 h; uh2 u; } c; c.h = h; return c.u;
}
__device__ __forceinline__ float lo_f(uh2 v){ union { uh2 u; __half2 h; } c; c.u = v; return __low2float(c.h); }
__device__ __forceinline__ float hi_f(uh2 v){ union { uh2 u; __half2 h; } c; c.u = v; return __high2float(c.h); }

// ---- DPP full-wave lane shifts (VALU, no DS pipe); invalid lane <- old ----
__device__ __forceinline__ uh2 dshr1(uh2 v, unsigned old){   // lane i <- lane i-1 (wave_shr:1)
    return (uh2)__builtin_amdgcn_update_dpp((int)old, (int)v, 0x138, 0xF, 0xF, false);
}
__device__ __forceinline__ uh2 dshl1(uh2 v, unsigned old){   // lane i <- lane i+1 (wave_shl:1)
    return (uh2)__builtin_amdgcn_update_dpp((int)old, (int)v, 0x130, 0xF, 0xF, false);
}

// one full 512-wide row: lane l holds halves [8l..8l+7] in 4 packed regs
struct R4 { uh2 a, b, c, d; };
__device__ __forceinline__ R4 r4splat(uh2 v){ R4 r; r.a=v; r.b=v; r.c=v; r.d=v; return r; }
__device__ __forceinline__ R4 ldrow(const float* p){
    float4 u = *(const float4*)p;
    float4 v = *(const float4*)(p + 4);
    R4 r; r.a = pk2(u.x,u.y); r.b = pk2(u.z,u.w); r.c = pk2(v.x,v.y); r.d = pk2(v.z,v.w);
    return r;
}
__device__ __forceinline__ R4 vmin3(const R4& x, const R4& y, const R4& z){
    R4 r; r.a=pmin3(x.a,y.a,z.a); r.b=pmin3(x.b,y.b,z.b); r.c=pmin3(x.c,y.c,z.c); r.d=pmin3(x.d,y.d,z.d); return r;
}
__device__ __forceinline__ R4 vmax3(const R4& x, const R4& y, const R4& z){
    R4 r; r.a=pmax3(x.a,y.a,z.a); r.b=pmax3(x.b,y.b,z.b); r.c=pmax3(x.c,y.c,z.c); r.d=pmax3(x.d,y.d,z.d); return r;
}
__device__ __forceinline__ R4 rmin(const R4& x, const R4& y){
    R4 r; r.a=pmin(x.a,y.a); r.b=pmin(x.b,y.b); r.c=pmin(x.c,y.c); r.d=pmin(x.d,y.d); return r;
}
__device__ __forceinline__ R4 rmax3(const R4& x, const R4& y, const R4& z){ return vmax3(x,y,z); }
__device__ __forceinline__ R4 relusub(const R4& p, const R4& d){
    R4 r; r.a=pmax(psub(p.a,d.a),0u); r.b=pmax(psub(p.b,d.b),0u);
          r.c=pmax(psub(p.c,d.c),0u); r.d=pmax(psub(p.d,d.d),0u); return r;
}
// s += d*(1-s)  (relu provably redundant for s,d in [0,1])
__device__ __forceinline__ void skupd2(R4& s, const R4& d){
    s.a = padd(s.a, pnfma(s.a,d.a));
    s.b = padd(s.b, pnfma(s.b,d.b));
    s.c = padd(s.c, pnfma(s.c,d.c));
    s.d = padd(s.d, pnfma(s.d,d.d));
}
// erode horizontal: min(left,right) excluding center (center is in the vertical min)
__device__ __forceinline__ R4 hminLR(const R4& x){
    uh2 L  = dshr1(x.d, PINF2);
    uh2 Rv = dshl1(x.a, PINF2);
    uh2 s0=alignh(L,x.a), s1=alignh(x.a,x.b), s2=alignh(x.b,x.c), s3=alignh(x.c,x.d), s4=alignh(x.d,Rv);
    R4 m; m.a=pmin(s0,s1); m.b=pmin(s1,s2); m.c=pmin(s2,s3); m.d=pmin(s3,s4); return m;
}
// dilate horizontal: 3-window max including center
__device__ __forceinline__ R4 hmax3w(const R4& x){
    uh2 L  = dshr1(x.d, NINF2);
    uh2 Rv = dshl1(x.a, NINF2);
    uh2 s0=alignh(L,x.a), s1=alignh(x.a,x.b), s2=alignh(x.b,x.c), s3=alignh(x.c,x.d), s4=alignh(x.d,Rv);
    R4 m; m.a=pmax3(s0,x.a,s1); m.b=pmax3(s1,x.b,s2); m.c=pmax3(s2,x.c,s3); m.d=pmax3(s3,x.d,s4); return m;
}

// ---------- FAST step: interior bands, no row guards, vertical-first dilate ----------
// f0 = row g (consumed now), f1 = row g+1; this step reloads f0 with row g+2.
// oc1/oc2 = other-row for THIS step's fin; on1/on2 loaded now for NEXT step.
__device__ __forceinline__ void step_fast(
    int g, int s, int y0, int y1,
    const float* __restrict__ img, const float* __restrict__ oth,
    R4& i2, R4& i1, R4& f0, R4& f1,
    R4& e1p, R4& e1pp, R4& e2p, R4& e2pp, R4& e3p, R4& e3pp, R4& e4p, R4& e4pp,
    R4& skB, R4& skD1, R4& skD2, R4& skF,
    float4& oc1, float4& oc2, float4& on1, float4& on2,
    float& sa, float& sb)
{
    R4 i0 = f0;
    if (s + 2 < NSTEP) f0 = ldrow(img + (size_t)(g + 2) * WW);   // 2-deep prefetch
    const int  yf   = g - 5;
    const bool fin  = (yf >= y0) && (yf < y1);
    const bool finN = (yf + 1 >= y0) && (yf + 1 < y1);
    if (finN) {                                                   // other-row 1 step early
        on1 = *(const float4*)(oth + (size_t)(yf + 1) * WW);
        on2 = *(const float4*)(oth + (size_t)(yf + 1) * WW + 4);
    }

    R4 e1n = rmin(vmin3(i2, i1, i0), hminLR(i1));
    R4 d1  = hmax3w(vmax3(e1pp, e1p, e1n));        // dilate(e1) @ g-2
    skB = relusub(i2, d1);

    R4 e2n = rmin(vmin3(e1pp, e1p, e1n), hminLR(e1p));
    R4 d2  = hmax3w(vmax3(e2pp, e2p, e2n));        // @ g-3
    skupd2(skD1, relusub(e1pp, d2));

    R4 e3n = rmin(vmin3(e2pp, e2p, e2n), hminLR(e2p));
    R4 d3  = hmax3w(vmax3(e3pp, e3p, e3n));        // @ g-4
    skupd2(skD2, relusub(e2pp, d3));

    R4 e4n = rmin(vmin3(e3pp, e3p, e3n), hminLR(e3p));
    R4 d4  = hmax3w(vmax3(e4pp, e4p, e4n));        // @ g-5
    skupd2(skF, relusub(e3pp, d4));

    if (fin) {
        float c0=lo_f(skF.a), c1=hi_f(skF.a), c2=lo_f(skF.b), c3=hi_f(skF.b);
        float c4=lo_f(skF.c), c5=hi_f(skF.c), c6=lo_f(skF.d), c7=hi_f(skF.d);
        sa += ((c0+c1)+(c2+c3)) + ((c4+c5)+(c6+c7));
        sb += ((c0*oc1.x + c1*oc1.y) + (c2*oc1.z + c3*oc1.w))
            + ((c4*oc2.x + c5*oc2.y) + (c6*oc2.z + c7*oc2.w));
    }
    i2 = i1; i1 = i0;
    e1pp = e1n; e2pp = e2n; e3pp = e3n; e4pp = e4n;   // caller swaps (p,pp)
}

// ---------- GUARD step: bands 0 / NBANDS-1 (proven logic, DPP, 2-deep prefetch) ----------
__device__ __forceinline__ void step_guard(
    int g, int s, int y0, int y1,
    const float* __restrict__ img, const float* __restrict__ oth,
    R4& i2, R4& i1, R4& f0, R4& f1,
    R4& e1p, R4& e1pp, R4& e2p, R4& e2pp, R4& e3p, R4& e3pp,
    R4& h1p, R4& h1pp, R4& h2p, R4& h2pp, R4& h3p, R4& h3pp,
    R4& h4p, R4& h4pp,
    R4& skB, R4& skD1, R4& skD2, R4& skF,
    float4& oc1, float4& oc2, float4& on1, float4& on2,
    float& sa, float& sb)
{
    R4 i0 = f0;
    {
        const int gn = g + 2;
        const bool ld = (s + 2 < NSTEP) && (gn >= 0) && (gn < HH);
        f0 = ld ? ldrow(img + (size_t)gn * WW) : r4splat(PINF2);
    }
    const int  yf   = g - 5;
    const bool fin  = (yf >= y0) && (yf < y1);
    const bool finN = (yf + 1 >= y0) && (yf + 1 < y1);
    if (finN) {
        on1 = *(const float4*)(oth + (size_t)(yf + 1) * WW);
        on2 = *(const float4*)(oth + (size_t)(yf + 1) * WW + 4);
    }

    R4 e1n = rmin(vmin3(i2, i1, i0), hminLR(i1));
    R4 h1n = hmax3w(e1n);
    if ((unsigned)(g - 1) >= (unsigned)HH) { e1n = r4splat(PINF2); h1n = r4splat(NINF2); }
    R4 d1 = rmax3(h1pp, h1p, h1n);
    skB = relusub(i2, d1);

    R4 e2n = rmin(vmin3(e1pp, e1p, e1n), hminLR(e1p));
    R4 h2n = hmax3w(e2n);
    if ((unsigned)(g - 2) >= (unsigned)HH) { e2n = r4splat(PINF2); h2n = r4splat(NINF2); }
    R4 d2 = rmax3(h2pp, h2p, h2n);
    skupd2(skD1, relusub(e1pp, d2));

    R4 e3n = rmin(vmin3(e2pp, e2p, e2n), hminLR(e2p));
    R4 h3n = hmax3w(e3n);
    if ((unsigned)(g - 3) >= (unsigned)HH) { e3n = r4splat(PINF2); h3n = r4splat(NINF2); }
    R4 d3 = rmax3(h3pp, h3p, h3n);
    skupd2(skD2, relusub(e2pp, d3));

    R4 e4n = rmin(vmin3(e3pp, e3p, e3n), hminLR(e3p));
    R4 h4n = hmax3w(e4n);
    if ((unsigned)(g - 4) >= (unsigned)HH) { h4n = r4splat(NINF2); }
    R4 d4 = rmax3(h4pp, h4p, h4n);
    skupd2(skF, relusub(e3pp, d4));

    if (fin) {
        float c0=lo_f(skF.a), c1=hi_f(skF.a), c2=lo_f(skF.b), c3=hi_f(skF.b);
        float c4=lo_f(skF.c), c5=hi_f(skF.c), c6=lo_f(skF.d), c7=hi_f(skF.d);
        sa += ((c0+c1)+(c2+c3)) + ((c4+c5)+(c6+c7));
        sb += ((c0*oc1.x + c1*oc1.y) + (c2*oc1.z + c3*oc1.w))
            + ((c4*oc2.x + c5*oc2.y) + (c6*oc2.z + c7*oc2.w));
    }
    i2 = i1; i1 = i0;
    e1pp = e1n; e2pp = e2n; e3pp = e3n;
    h1pp = h1n; h2pp = h2n; h3pp = h3n; h4pp = h4n;
}

__global__ __launch_bounds__(256, 2)
void cldice_stream_k(const float* __restrict__ y_pred,
                     const float* __restrict__ y_true,
                     float2* __restrict__ partials, int B)
{
    const int lane = threadIdx.x & 63;
    const int wid  = threadIdx.x >> 6;
    const int wave = blockIdx.x * 4 + wid;
    const int nPerChain = B * NBANDS;
    if (wave >= 2 * nPerChain) return;
    const int chain = wave / nPerChain;
    const int rem   = wave - chain * nPerChain;
    const int im    = rem >> 5;                 // NBANDS == 32
    const int band  = rem & (NBANDS - 1);
    const int y0 = band * BAND;
    const int y1 = y0 + BAND;

    const float* __restrict__ img = (chain ? y_true : y_pred) + (size_t)im * NPIX + lane * 8;
    const float* __restrict__ oth = (chain ? y_pred : y_true) + (size_t)im * NPIX + lane * 8;

    R4 sk0 = r4splat(0u), sk1 = sk0, sk2 = sk0, sk3 = sk0;
    float sa = 0.f, sb = 0.f;
    const int g0 = y0 - 5;
    float4 oA1 = make_float4(0,0,0,0), oA2 = oA1, oB1 = oA1, oB2 = oA1;

    if (band == 0 || band == NBANDS - 1) {
        // -------- guarded path (image top/bottom) --------
        R4 i2 = r4splat(PINF2), i1 = i2;
        R4 e1A = i2, e1B = i2, e2A = i2, e2B = i2, e3A = i2, e3B = i2;
        R4 h1A = r4splat(NINF2), h1B = h1A, h2A = h1A, h2B = h1A;
        R4 h3A = h1A, h3B = h1A, h4A = h1A, h4B = h1A;
        R4 f0 = (g0 >= 0)     ? ldrow(img + (size_t)g0 * WW)       : r4splat(PINF2);
        R4 f1 = (g0 + 1 >= 0) ? ldrow(img + (size_t)(g0 + 1) * WW) : r4splat(PINF2);

#define STEPG(U, E1P,E1PP, E2P,E2PP, E3P,E3PP, H1P,H1PP, H2P,H2PP, H3P,H3PP, H4P,H4PP, SKB,SKD1,SKD2,SKF, FA,FB, OC1,OC2,ON1,ON2) \
        step_guard(g0 + sbase + U, sbase + U, y0, y1, img, oth, i2, i1, FA, FB, \
                   E1P,E1PP, E2P,E2PP, E3P,E3PP, H1P,H1PP, H2P,H2PP, H3P,H3PP, H4P,H4PP, \
                   SKB,SKD1,SKD2,SKF, OC1,OC2,ON1,ON2, sa, sb)
        for (int sbase = 0; sbase < 24; sbase += 4) {
            STEPG(0, e1A,e1B, e2A,e2B, e3A,e3B, h1A,h1B, h2A,h2B, h3A,h3B, h4A,h4B, sk1,sk0,sk3,sk2, f0,f1, oA1,oA2,oB1,oB2);
            STEPG(1, e1B,e1A, e2B,e2A, e3B,e3A, h1B,h1A, h2B,h2A, h3B,h3A, h4B,h4A, sk2,sk1,sk0,sk3, f1,f0, oB1,oB2,oA1,oA2);
            STEPG(2, e1A,e1B, e2A,e2B, e3A,e3B, h1A,h1B, h2A,h2B, h3A,h3B, h4A,h4B, sk3,sk2,sk1,sk0, f0,f1, oA1,oA2,oB1,oB2);
            STEPG(3, e1B,e1A, e2B,e2A, e3B,e3A, h1B,h1A, h2B,h2A, h3B,h3A, h4B,h4A, sk0,sk3,sk2,sk1, f1,f0, oB1,oB2,oA1,oA2);
        }
        {   // tail: steps 24, 25 (last fin at 25)
            const int sbase = 24;
            STEPG(0, e1A,e1B, e2A,e2B, e3A,e3B, h1A,h1B, h2A,h2B, h3A,h3B, h4A,h4B, sk1,sk0,sk3,sk2, f0,f1, oA1,oA2,oB1,oB2);
            STEPG(1, e1B,e1A, e2B,e2A, e3B,e3A, h1B,h1A, h2B,h2A, h3B,h3A, h4B,h4A, sk2,sk1,sk0,sk3, f1,f0, oB1,oB2,oA1,oA2);
        }
#undef STEPG
    } else {
        // -------- fast path (interior bands; all halo rows are real) --------
        R4 i2 = ldrow(img + (size_t)g0 * WW);       // harmless warm init (rows valid)
        R4 i1 = i2;
        R4 e1A = r4splat(PINF2), e1B = e1A, e2A = e1A, e2B = e1A;
        R4 e3A = e1A, e3B = e1A, e4A = e1A, e4B = e1A;
        R4 f0 = i2;
        R4 f1 = ldrow(img + (size_t)(g0 + 1) * WW);

#define STEPF(U, E1P,E1PP, E2P,E2PP, E3P,E3PP, E4P,E4PP, SKB,SKD1,SKD2,SKF, FA,FB, OC1,OC2,ON1,ON2) \
        step_fast(g0 + sbase + U, sbase + U, y0, y1, img, oth, i2, i1, FA, FB, \
                  E1P,E1PP, E2P,E2PP, E3P,E3PP, E4P,E4PP, SKB,SKD1,SKD2,SKF, \
                  OC1,OC2,ON1,ON2, sa, sb)
        for (int sbase = 0; sbase < 24; sbase += 4) {
            STEPF(0, e1A,e1B, e2A,e2B, e3A,e3B, e4A,e4B, sk1,sk0,sk3,sk2, f0,f1, oA1,oA2,oB1,oB2);
            STEPF(1, e1B,e1A, e2B,e2A, e3B,e3A, e4B,e4A, sk2,sk1,sk0,sk3, f1,f0, oB1,oB2,oA1,oA2);
            STEPF(2, e1A,e1B, e2A,e2B, e3A,e3B, e4A,e4B, sk3,sk2,sk1,sk0, f0,f1, oA1,oA2,oB1,oB2);
            STEPF(3, e1B,e1A, e2B,e2A, e3B,e3A, e4B,e4A, sk0,sk3,sk2,sk1, f1,f0, oB1,oB2,oA1,oA2);
        }
        {   // tail: steps 24, 25
            const int sbase = 24;
            STEPF(0, e1A,e1B, e2A,e2B, e3A,e3B, e4A,e4B, sk1,sk0,sk3,sk2, f0,f1, oA1,oA2,oB1,oB2);
            STEPF(1, e1B,e1A, e2B,e2A, e3B,e3A, e4B,e4A, sk2,sk1,sk0,sk3, f1,f0, oB1,oB2,oA1,oA2);
        }
#undef STEPF
    }

#pragma unroll
    for (int off = 32; off; off >>= 1) {
        sa += __shfl_down(sa, off);
        sb += __shfl_down(sb, off);
    }
    if (lane == 0) partials[wave] = make_float2(sb, sa);   // (.x = sum skel*other, .y = sum skel)
}

__global__ void cldice_final_k(const float2* __restrict__ partials, int nW,
                               float* __restrict__ out)
{
    double s0 = 0, s1 = 0, s2 = 0, s3 = 0;
    for (int i = threadIdx.x; i < nW; i += 256) {
        float2 p = partials[i];        s0 += p.x; s1 += p.y;   // chain 0: skel_pred
        float2 q = partials[nW + i];   s2 += q.x; s3 += q.y;   // chain 1: skel_true
    }
#pragma unroll
    for (int off = 32; off; off >>= 1) {
        s0 += __shfl_down(s0, off);
        s1 += __shfl_down(s1, off);
        s2 += __shfl_down(s2, off);
        s3 += __shfl_down(s3, off);
    }
    __shared__ double sm[4][4];
    int wid = threadIdx.x >> 6, lane = threadIdx.x & 63;
    if (lane == 0) { sm[0][wid] = s0; sm[1][wid] = s1; sm[2][wid] = s2; sm[3][wid] = s3; }
    __syncthreads();
    if (threadIdx.x == 0) {
        double S0 = sm[0][0] + sm[0][1] + sm[0][2] + sm[0][3];
        double S1 = sm[1][0] + sm[1][1] + sm[1][2] + sm[1][3];
        double S2 = sm[2][0] + sm[2][1] + sm[2][2] + sm[2][3];
        double S3 = sm[3][0] + sm[3][1] + sm[3][2] + sm[3][3];
        double tprec = (S0 + 1.0) / (S1 + 1.0);
        double tsens = (S2 + 1.0) / (S3 + 1.0);
        out[0] = (float)(1.0 - 2.0 * (tprec * tsens) / (tprec + tsens));
    }
}

extern "C" void kernel_launch(void* const* d_in, const int* in_sizes, int n_in,
                              void* d_out, int out_size, void* d_ws, size_t ws_size,
                              hipStream_t stream)
{
    const float* y_pred = (const float*)d_in[0];
    const float* y_true = (const float*)d_in[1];
    const int B = in_sizes[0] / NPIX;          // 32 images

    float2* partials = (float2*)d_ws;          // 2*B*NBANDS float2 = 16 KB
    const int nWaves = 2 * B * NBANDS;
    const int blocks = (nWaves + 3) / 4;       // 4 waves per 256-thread block
    cldice_stream_k<<<blocks, 256, 0, stream>>>(y_pred, y_true, partials, B);

    cldice_final_k<<<1, 256, 0, stream>>>(partials, B * NBANDS, (float*)d_out);
}